// Round 11
// baseline (2761.971 us; speedup 1.0000x reference)
//
#include <hip/hip_runtime.h>
#include <stdint.h>

// ---------- types & helpers ----------
typedef __bf16 bf16x8 __attribute__((ext_vector_type(8)));
typedef float  f32x4  __attribute__((ext_vector_type(4)));
typedef unsigned short u16x8 __attribute__((ext_vector_type(8)));

__device__ __forceinline__ unsigned short f2bf(float f) {
    union { float f; uint32_t u; } x; x.f = f;
    uint32_t r = (x.u + 0x7FFFu + ((x.u >> 16) & 1u)) >> 16;
    return (unsigned short)r;
}
__device__ __forceinline__ float bf2f(unsigned short b) {
    union { uint32_t u; float f; } x; x.u = ((uint32_t)b) << 16;
    return x.f;
}

// global -> LDS direct (16B per lane). LDS dest: wave-uniform base + lane*16.
__device__ __forceinline__ void gl16(const void* g, void* l) {
    __builtin_amdgcn_global_load_lds(
        (const __attribute__((address_space(1))) void*)g,
        (__attribute__((address_space(3))) void*)(uint32_t)(uintptr_t)l,
        16, 0, 0);
}

#define MFMA16(a, b, c) __builtin_amdgcn_mfma_f32_16x16x32_bf16((a), (b), (c), 0, 0, 0)

// ---------- elementwise f32 -> bf16 ----------
__global__ __launch_bounds__(256) void f32_to_bf16_kernel(const float* __restrict__ in,
                                                          unsigned short* __restrict__ out,
                                                          int n8) {
    int i = blockIdx.x * 256 + threadIdx.x;
    if (i >= n8) return;
    float4 a = ((const float4*)in)[2 * i];
    float4 b = ((const float4*)in)[2 * i + 1];
    u16x8 o;
    o[0] = f2bf(a.x); o[1] = f2bf(a.y); o[2] = f2bf(a.z); o[3] = f2bf(a.w);
    o[4] = f2bf(b.x); o[5] = f2bf(b.y); o[6] = f2bf(b.z); o[7] = f2bf(b.w);
    ((u16x8*)out)[i] = o;
}

// ---------- tiled transpose f32[R][C] -> bf16 out[C][R], 64x64 tiles ----------
__global__ __launch_bounds__(256) void transpose_w_kernel(const float* __restrict__ in,
                                                          unsigned short* __restrict__ out,
                                                          int R, int C) {
    __shared__ float tile[64][65];
    int c0 = blockIdx.x * 64, r0 = blockIdx.y * 64;
    int tid = threadIdx.x;
    int tr = tid >> 4;
    int tc4 = (tid & 15) * 4;
#pragma unroll
    for (int it = 0; it < 4; ++it) {
        int r = it * 16 + tr;
        float4 v = *(const float4*)&in[(size_t)(r0 + r) * C + c0 + tc4];
        tile[r][tc4] = v.x; tile[r][tc4 + 1] = v.y;
        tile[r][tc4 + 2] = v.z; tile[r][tc4 + 3] = v.w;
    }
    __syncthreads();
#pragma unroll
    for (int it = 0; it < 4; ++it) {
        int c = it * 16 + tr;
        ushort4 o;
        o.x = f2bf(tile[tc4][c]);
        o.y = f2bf(tile[tc4 + 1][c]);
        o.z = f2bf(tile[tc4 + 2][c]);
        o.w = f2bf(tile[tc4 + 3][c]);
        *(ushort4*)&out[(size_t)(c0 + c) * R + r0 + tc4] = o;
    }
}

// ====== 256x256 tile, BK=32, 64KB LDS -> 2 WG/CU, R7-family schedule ========
// Per K-tile(32): reads 12 b128 (afR0 4, afR1 4, bC0 2, bC1 2), 4 gl16 stage,
// 32 MFMA in 4 quadrant-phases; one lgkm(0)+vmcnt(0)+barrier at PH2.
// Swizzle: 64B rows, byte ^= (row&3)<<4; staging linear dest + inv-swz src.
__global__ __launch_bounds__(512, 4) void gemm_qkvgate_kernel(const unsigned short* __restrict__ A,
                                                              const unsigned short* __restrict__ Bt,
                                                              unsigned short* __restrict__ qkvp,
                                                              unsigned short* __restrict__ gatep,
                                                              int K, int NBN, int NQ) {
    __shared__ unsigned short Abuf[2][2][4096];  // [slot][half][128*32] 8KB
    __shared__ unsigned short Bbuf[2][2][4096];

    int bid = blockIdx.x;
    int xcd = bid & 7, kw = bid >> 3;            // 2D XCD-region swizzle
    int bm = (xcd & 3) * 4 + (kw & 3);
    int bn = (xcd >> 2) * (NBN >> 1) + (kw >> 2);
    int tid = threadIdx.x, lane = tid & 63, w = tid >> 6;
    int wr = w >> 2, wc = w & 3;

    // staging: half-tile = 128 rows x 64B; 1 gl16/thread (512x16B = 8KB)
    int r0 = tid >> 2;                 // 0..127
    int cbs = (tid & 3) << 4;          // 0,16,32,48
    int el0 = (cbs ^ ((r0 & 3) << 4)) >> 1;
    int lo0 = tid * 16;

    const unsigned short* Ag0 = A + (size_t)(bm * 256) * K;
    const unsigned short* Ag1 = A + (size_t)(bm * 256 + 128) * K;
    const unsigned short* Bg0 = Bt + (size_t)(bn * 256) * K;
    const unsigned short* Bg1 = Bt + (size_t)(bn * 256 + 128) * K;

#define STAGE(src, dstHalf, k0) \
    gl16((src) + (size_t)r0 * K + (k0) + el0, (char*)(dstHalf) + lo0)

    // fragment addressing: row stride 64B; swz depends on row&3 (const/lane)
    int aRow = wr * 64 + (lane & 15);
    int bRow = wc * 32 + (lane & 15);
    int swzA = (aRow & 3) << 4;
    int swzB = (bRow & 3) << 4;
    int cbb = (lane >> 4) << 4;

#define RD_A(slot, R, m) \
    af[R][m] = *(const bf16x8*)((const char*)Abuf[slot][R] + ((aRow + (m) * 16) << 6) + (cbb ^ swzA))
#define RD_B(slot, Cq, n) \
    bfr[Cq][n] = *(const bf16x8*)((const char*)Bbuf[slot][Cq] + ((bRow + (n) * 16) << 6) + (cbb ^ swzB))

#define QUAD(q, Rh, Cc)                                                       \
    do {                                                                      \
        _Pragma("unroll")                                                     \
        for (int m = 0; m < 4; ++m)                                           \
            _Pragma("unroll")                                                 \
            for (int n = 0; n < 2; ++n)                                       \
                acc[q][m][n] = MFMA16(af[Rh][m], bfr[Cc][n], acc[q][m][n]);   \
    } while (0)

    bf16x8 af[2][4];
    bf16x8 bfr[2][2];
    f32x4 acc[4][4][2];
#pragma unroll
    for (int q = 0; q < 4; ++q)
#pragma unroll
        for (int m = 0; m < 4; ++m)
#pragma unroll
            for (int n = 0; n < 2; ++n)
#pragma unroll
                for (int r = 0; r < 4; ++r) acc[q][m][n][r] = 0.f;

    int NT = K >> 5;   // 64
    // prologue: tile0 -> slot0, tile1 -> slot1
    STAGE(Ag0, Abuf[0][0], 0);
    STAGE(Bg0, Bbuf[0][0], 0);
    STAGE(Ag1, Abuf[0][1], 0);
    STAGE(Bg1, Bbuf[0][1], 0);
    STAGE(Ag0, Abuf[1][0], 32);
    STAGE(Bg0, Bbuf[1][0], 32);
    STAGE(Ag1, Abuf[1][1], 32);
    STAGE(Bg1, Bbuf[1][1], 32);
    asm volatile("s_waitcnt vmcnt(4)" ::: "memory");
    __builtin_amdgcn_s_barrier();
#pragma unroll
    for (int m = 0; m < 4; ++m) RD_A(0, 0, m);
#pragma unroll
    for (int n = 0; n < 2; ++n) RD_B(0, 0, n);

    for (int t = 0; t < NT; ++t) {
        int cur = t & 1, nx = cur ^ 1;
        bool rd = (t + 1 < NT);
        bool st = (t + 2 < NT);
        int ks = (t + 2) << 5;

        // ---- PH0: read afR1(t); Q0 gated on afR0+bC0 (read 2 phases back)
#pragma unroll
        for (int m = 0; m < 4; ++m) RD_A(cur, 1, m);
        asm volatile("s_waitcnt lgkmcnt(4)" ::: "memory");
        __builtin_amdgcn_sched_barrier(0);
        __builtin_amdgcn_s_setprio(1);
        QUAD(0, 0, 0);
        __builtin_amdgcn_s_setprio(0);

        // ---- PH1: read bC1(t); Q1 gated on afR1
#pragma unroll
        for (int n = 0; n < 2; ++n) RD_B(cur, 1, n);
        asm volatile("s_waitcnt lgkmcnt(2)" ::: "memory");
        __builtin_amdgcn_sched_barrier(0);
        __builtin_amdgcn_s_setprio(1);
        QUAD(1, 1, 0);
        __builtin_amdgcn_s_setprio(0);

        // ---- PH2: tile-boundary drain; stage A0,B0 of t+2; read bC0(t+1)
        asm volatile("s_waitcnt lgkmcnt(0)" ::: "memory");
        asm volatile("s_waitcnt vmcnt(0)" ::: "memory");
        __builtin_amdgcn_s_barrier();
        if (st) {
            STAGE(Ag0, Abuf[cur][0], ks);
            STAGE(Bg0, Bbuf[cur][0], ks);
        }
        if (rd) {
#pragma unroll
            for (int n = 0; n < 2; ++n) RD_B(nx, 0, n);
        }
        __builtin_amdgcn_s_setprio(1);
        QUAD(2, 0, 1);
        __builtin_amdgcn_s_setprio(0);

        // ---- PH3: stage A1,B1 of t+2; read afR0(t+1); Q3 all-reg
        if (st) {
            STAGE(Ag1, Abuf[cur][1], ks);
            STAGE(Bg1, Bbuf[cur][1], ks);
        }
        if (rd) {
#pragma unroll
            for (int m = 0; m < 4; ++m) RD_A(nx, 0, m);
        }
        __builtin_amdgcn_s_setprio(1);
        QUAD(3, 1, 1);
        __builtin_amdgcn_s_setprio(0);
    }

    // epilogue: block-uniform output select
    bool isQ = (bn < NQ);
    unsigned short* outp = isQ ? qkvp : gatep;
    int Nout = isQ ? 12288 : 4096;
    int colb0 = (isQ ? bn : bn - NQ) * 256;
#pragma unroll
    for (int q = 0; q < 4; ++q) {
        const int R_ = q & 1, C_ = q >> 1;
#pragma unroll
        for (int m = 0; m < 4; ++m) {
            int row0 = bm * 256 + R_ * 128 + wr * 64 + m * 16 + ((lane >> 4) * 4);
#pragma unroll
            for (int n = 0; n < 2; ++n) {
                int col = colb0 + C_ * 128 + wc * 32 + n * 16 + (lane & 15);
#pragma unroll
                for (int rg = 0; rg < 4; ++rg) {
                    float v = acc[q][m][n][rg];
                    float sig = 1.f / (1.f + __expf(-v));
                    float r = isQ ? v * sig : sig;
                    outp[(size_t)(row0 + rg) * Nout + col] = f2bf(r);
                }
            }
        }
    }
#undef STAGE
#undef RD_A
#undef RD_B
#undef QUAD
}

// ====== 128x128 pipelined out-GEMM (R7-style single-barrier gates) ==========
__global__ __launch_bounds__(256, 2) void gemm_out_kernel(const unsigned short* __restrict__ A,
                                                          const unsigned short* __restrict__ Bt,
                                                          float* __restrict__ Cout,
                                                          int N, int K, int NBN) {
    __shared__ unsigned short Abuf[2][2][4096];  // [slot][half][64*64] 8KB
    __shared__ unsigned short Bbuf[2][2][4096];

    int bid = blockIdx.x, nwg = gridDim.x;
    int wg = (bid & 7) * (nwg >> 3) + (bid >> 3);   // 1D XCD chunk swizzle
    int bm = wg / NBN, bn = wg % NBN;
    int tid = threadIdx.x, lane = tid & 63, w = tid >> 6;
    int wr = w >> 1, wc = w & 1;

    int r0 = tid >> 3;                  // 0..31
    int cbs = (tid & 7) << 4;
    int el0 = (cbs ^ ((r0 & 7) << 4)) >> 1;
    int r1 = 32 + r0;
    int el1 = (cbs ^ ((r1 & 7) << 4)) >> 1;
    int lo0 = tid * 16, lo1 = 4096 + tid * 16;

    const unsigned short* Ag0 = A + (size_t)(bm * 128) * K;
    const unsigned short* Ag1 = A + (size_t)(bm * 128 + 64) * K;
    const unsigned short* Bg0 = Bt + (size_t)(bn * 128) * K;
    const unsigned short* Bg1 = Bt + (size_t)(bn * 128 + 64) * K;

#define STAGE(src, dstHalf, k0)                                            \
    do {                                                                   \
        gl16((src) + (size_t)r0 * K + (k0) + el0, (char*)(dstHalf) + lo0); \
        gl16((src) + (size_t)r1 * K + (k0) + el1, (char*)(dstHalf) + lo1); \
    } while (0)

    int aRow = wr * 32 + (lane & 15);
    int bRow = wc * 32 + (lane & 15);
    int swz = (lane & 7) << 4;
    int cbb = (lane >> 4) << 4;

#define RD_A(slot, R, m, kk) \
    af[R][m][kk] = *(const bf16x8*)((const char*)Abuf[slot][R] + ((aRow + (m) * 16) << 7) + (((kk) * 64 + cbb) ^ swz))
#define RD_B(slot, Cq, n, kk) \
    bfr[Cq][n][kk] = *(const bf16x8*)((const char*)Bbuf[slot][Cq] + ((bRow + (n) * 16) << 7) + (((kk) * 64 + cbb) ^ swz))

#define QUAD(q, Rh, Cc)                                                       \
    do {                                                                      \
        _Pragma("unroll")                                                     \
        for (int m = 0; m < 2; ++m)                                           \
            _Pragma("unroll")                                                 \
            for (int n = 0; n < 2; ++n) {                                     \
                acc[q][m][n] = MFMA16(af[Rh][m][0], bfr[Cc][n][0], acc[q][m][n]); \
                acc[q][m][n] = MFMA16(af[Rh][m][1], bfr[Cc][n][1], acc[q][m][n]); \
            }                                                                 \
    } while (0)

    bf16x8 af[2][2][2];
    bf16x8 bfr[2][2][2];
    f32x4 acc[4][2][2];
#pragma unroll
    for (int q = 0; q < 4; ++q)
#pragma unroll
        for (int m = 0; m < 2; ++m)
#pragma unroll
            for (int n = 0; n < 2; ++n)
#pragma unroll
                for (int r = 0; r < 4; ++r) acc[q][m][n][r] = 0.f;

    int NT = K >> 6;
    STAGE(Ag0, Abuf[0][0], 0);
    STAGE(Bg0, Bbuf[0][0], 0);
    STAGE(Ag1, Abuf[0][1], 0);
    STAGE(Bg1, Bbuf[0][1], 0);
    STAGE(Ag0, Abuf[1][0], 64);
    STAGE(Bg0, Bbuf[1][0], 64);
    STAGE(Ag1, Abuf[1][1], 64);
    STAGE(Bg1, Bbuf[1][1], 64);
    asm volatile("s_waitcnt vmcnt(8)" ::: "memory");
    __builtin_amdgcn_s_barrier();
#pragma unroll
    for (int m = 0; m < 2; ++m) { RD_A(0, 0, m, 0); RD_A(0, 0, m, 1); }
#pragma unroll
    for (int n = 0; n < 2; ++n) { RD_B(0, 0, n, 0); RD_B(0, 0, n, 1); }

    for (int t = 0; t < NT; ++t) {
        int cur = t & 1, nx = cur ^ 1;
        bool rd = (t + 1 < NT);
        bool st = (t + 2 < NT);
        int ks = (t + 2) << 6;

        // ---- PH0
#pragma unroll
        for (int m = 0; m < 2; ++m) { RD_A(cur, 1, m, 0); RD_A(cur, 1, m, 1); }
        asm volatile("s_waitcnt lgkmcnt(4)" ::: "memory");
        __builtin_amdgcn_sched_barrier(0);
        __builtin_amdgcn_s_setprio(1);
        QUAD(0, 0, 0);
        __builtin_amdgcn_s_setprio(0);

        // ---- PH1
#pragma unroll
        for (int n = 0; n < 2; ++n) { RD_B(cur, 1, n, 0); RD_B(cur, 1, n, 1); }
        asm volatile("s_waitcnt lgkmcnt(4)" ::: "memory");
        __builtin_amdgcn_sched_barrier(0);
        __builtin_amdgcn_s_setprio(1);
        QUAD(1, 1, 0);
        __builtin_amdgcn_s_setprio(0);

        // ---- PH2: single tile-boundary drain
        asm volatile("s_waitcnt lgkmcnt(0)" ::: "memory");
        asm volatile("s_waitcnt vmcnt(0)" ::: "memory");
        __builtin_amdgcn_s_barrier();
        if (st) {
            STAGE(Ag0, Abuf[cur][0], ks);
            STAGE(Bg0, Bbuf[cur][0], ks);
        }
        if (rd) {
#pragma unroll
            for (int n = 0; n < 2; ++n) { RD_B(nx, 0, n, 0); RD_B(nx, 0, n, 1); }
        }
        __builtin_amdgcn_s_setprio(1);
        QUAD(2, 0, 1);
        __builtin_amdgcn_s_setprio(0);

        // ---- PH3
        if (st) {
            STAGE(Ag1, Abuf[cur][1], ks);
            STAGE(Bg1, Bbuf[cur][1], ks);
        }
        if (rd) {
#pragma unroll
            for (int m = 0; m < 2; ++m) { RD_A(nx, 0, m, 0); RD_A(nx, 0, m, 1); }
        }
        __builtin_amdgcn_s_setprio(1);
        QUAD(3, 1, 1);
        __builtin_amdgcn_s_setprio(0);
    }

    // epilogue (f32 out)
#pragma unroll
    for (int q = 0; q < 4; ++q) {
        const int R_ = q & 1, C_ = q >> 1;
#pragma unroll
        for (int m = 0; m < 2; ++m) {
            int row0 = bm * 128 + R_ * 64 + wr * 32 + m * 16 + ((lane >> 4) * 4);
#pragma unroll
            for (int n = 0; n < 2; ++n) {
                int col = bn * 128 + C_ * 64 + wc * 32 + n * 16 + (lane & 15);
#pragma unroll
                for (int rg = 0; rg < 4; ++rg)
                    Cout[(size_t)(row0 + rg) * N + col] = acc[q][m][n][rg];
            }
        }
    }
#undef STAGE
#undef RD_A
#undef RD_B
#undef QUAD
}

// ---------- qkv -> kts (scaled, transposed), vt (transposed); 64x64 tiles ----------
__global__ __launch_bounds__(256) void kv_transpose_kernel(const unsigned short* __restrict__ qkv,
                                                           const float* __restrict__ slopes,
                                                           unsigned short* __restrict__ kts,
                                                           unsigned short* __restrict__ vt) {
    __shared__ unsigned short tk[64][66];
    __shared__ unsigned short tv[64][66];
    int n0 = blockIdx.x * 64, d0 = blockIdx.y * 64, h = blockIdx.z;
    float s = slopes[h];
    int tid = threadIdx.x;
    int tr = tid >> 4;          // 0..15
    int tc4 = (tid & 15) * 4;   // 0..60
#pragma unroll
    for (int it = 0; it < 4; ++it) {
        int r = it * 16 + tr;
        int n = n0 + r;
        size_t rowb = (size_t)n * 12288 + h * 384;
        float sc = __expf(-s * (float)(255 - (n & 255)));
        ushort4 k4 = *(const ushort4*)&qkv[rowb + 128 + d0 + tc4];
        ushort4 v4 = *(const ushort4*)&qkv[rowb + 256 + d0 + tc4];
        tk[r][tc4 + 0] = f2bf(bf2f(k4.x) * sc);
        tk[r][tc4 + 1] = f2bf(bf2f(k4.y) * sc);
        tk[r][tc4 + 2] = f2bf(bf2f(k4.z) * sc);
        tk[r][tc4 + 3] = f2bf(bf2f(k4.w) * sc);
        tv[r][tc4 + 0] = v4.x;
        tv[r][tc4 + 1] = v4.y;
        tv[r][tc4 + 2] = v4.z;
        tv[r][tc4 + 3] = v4.w;
    }
    __syncthreads();
#pragma unroll
    for (int it = 0; it < 4; ++it) {
        int c = it * 16 + tr;
        ushort4 ok, ov;
        ok.x = tk[tc4 + 0][c]; ok.y = tk[tc4 + 1][c];
        ok.z = tk[tc4 + 2][c]; ok.w = tk[tc4 + 3][c];
        ov.x = tv[tc4 + 0][c]; ov.y = tv[tc4 + 1][c];
        ov.z = tv[tc4 + 2][c]; ov.w = tv[tc4 + 3][c];
        size_t ob = (size_t)(h * 128 + d0 + c) * 4096 + n0 + tc4;
        *(ushort4*)&kts[ob] = ok;
        *(ushort4*)&vt[ob] = ov;
    }
}

// ---------- per-block KV outer product ----------
__global__ __launch_bounds__(256) void kv_outer_kernel(const unsigned short* __restrict__ kts,
                                                       const unsigned short* __restrict__ vt,
                                                       float* __restrict__ U) {
    __shared__ unsigned short Kc[128 * 64];
    __shared__ unsigned short Vc[128 * 64];
    int blk = blockIdx.x;
    int h = blk & 31, t = blk >> 5;
    int tid = threadIdx.x, lane = tid & 63, w = tid >> 6;

    f32x4 acc[2][8];
#pragma unroll
    for (int m = 0; m < 2; ++m)
#pragma unroll
        for (int n = 0; n < 8; ++n)
#pragma unroll
            for (int r = 0; r < 4; ++r) acc[m][n][r] = 0.f;

    for (int ks = 0; ks < 4; ++ks) {
        __syncthreads();
#pragma unroll
        for (int it = 0; it < 4; ++it) {
            int slot = it * 256 + tid;
            int o = slot * 16;
            int r = o >> 7;
            int cb = o & 127;
            int scb = cb ^ ((r & 7) << 4);
            size_t j = (size_t)t * 256 + ks * 64 + (scb >> 1);
            gl16(kts + (size_t)(h * 128 + r) * 4096 + j, (char*)Kc + o);
            gl16(vt + (size_t)(h * 128 + r) * 4096 + j, (char*)Vc + o);
        }
        __syncthreads();
#pragma unroll
        for (int kk = 0; kk < 2; ++kk) {
            int kb = kk * 64 + ((lane >> 4) * 16);
            bf16x8 vf[2], kf[8];
#pragma unroll
            for (int m = 0; m < 2; ++m) {
                int e = w * 32 + m * 16 + (lane & 15);
                vf[m] = *(const bf16x8*)((const char*)Vc + (e << 7) + (kb ^ ((e & 7) << 4)));
            }
#pragma unroll
            for (int n = 0; n < 8; ++n) {
                int d = n * 16 + (lane & 15);
                kf[n] = *(const bf16x8*)((const char*)Kc + (d << 7) + (kb ^ ((d & 7) << 4)));
            }
#pragma unroll
            for (int m = 0; m < 2; ++m)
#pragma unroll
                for (int n = 0; n < 8; ++n)
                    acc[m][n] = MFMA16(vf[m], kf[n], acc[m][n]);
        }
    }
    size_t base = (size_t)(h * 16 + t) * 16384;
#pragma unroll
    for (int m = 0; m < 2; ++m)
#pragma unroll
        for (int n = 0; n < 8; ++n)
#pragma unroll
            for (int r = 0; r < 4; ++r) {
                int e = w * 32 + m * 16 + ((lane >> 4) * 4) + r;
                int d = n * 16 + (lane & 15);
                U[base + (size_t)e * 128 + d] = acc[m][n][r];
            }
}

// ---------- parallel scan: 32 heads x 16 chunks of 1024 ----------
__global__ __launch_bounds__(256) void kv_scan_kernel(const float* __restrict__ kv_cache,
                                                      const float* __restrict__ U,
                                                      const float* __restrict__ slopes,
                                                      unsigned short* __restrict__ Wb) {
    __shared__ float Tt[8][132];
    int h = blockIdx.x >> 4;
    int c = blockIdx.x & 15;
    int c0 = c * 1024, e0 = c * 8;
    int tid = threadIdx.x;
    float s = slopes[h];
    float bd = __expf(-s * 256.f);
    size_t hb = (size_t)h * 16384;
    // coalesced-ish read of kv_cache[h][d][e0..e0+8) -> Tt[e][d]
#pragma unroll
    for (int it = 0; it < 4; ++it) {
        int d = it * 32 + (tid >> 3);
        Tt[tid & 7][d] = kv_cache[hb + (size_t)d * 128 + e0 + (tid & 7)];
    }
    __syncthreads();
    float wst[4];
#pragma unroll
    for (int i = 0; i < 4; ++i) {
        int local = i * 256 + tid;
        wst[i] = Tt[local >> 7][local & 127];
    }
    for (int t = 0; t < 16; ++t) {
        size_t base = (size_t)(h * 16 + t) * 16384 + c0;
#pragma unroll
        for (int i = 0; i < 4; ++i) {
            int idx = i * 256 + tid;
            Wb[base + idx] = f2bf(wst[i]);
            wst[i] = bd * wst[i] + U[base + idx];
        }
    }
}

// ---------- fused attention block kernel: QBLK=128, 80KB LDS, 2 WG/CU ----------
__global__ __launch_bounds__(256, 2) void attn_out_kernel(const unsigned short* __restrict__ qkv,
                                                          const unsigned short* __restrict__ vt,
                                                          const unsigned short* __restrict__ Wb,
                                                          const float* __restrict__ slopes,
                                                          unsigned short* __restrict__ attn) {
    __shared__ unsigned short lds[40960];  // 80 KB
    unsigned short* Qs = lds;
    unsigned short* Ps = lds + 16384;
    unsigned short* KW = lds + 24576;
    unsigned short* Ks = KW;
    unsigned short* Vs = KW + 8192;

    int blk = blockIdx.x;
    int h = blk & 31, tq = blk >> 5;
    int t = tq >> 1, qh = tq & 1;
    float s = slopes[h];
    int tid = threadIdx.x, lane = tid & 63, w = tid >> 6;
    int rowbase = t * 256 + qh * 128;

#pragma unroll
    for (int it = 0; it < 8; ++it) {
        int o = (it * 256 + tid) * 16;
        int r = o >> 8, cb = o & 255, scb = cb ^ ((r & 7) << 4);
        gl16(qkv + (size_t)(rowbase + r) * 12288 + h * 384 + (scb >> 1), (char*)Qs + o);
    }
#pragma unroll
    for (int it = 0; it < 8; ++it) {
        int o = (it * 256 + tid) * 16;
        int e = o >> 8, cb = o & 255, scb = cb ^ ((e & 7) << 4);
        gl16(Wb + (size_t)((h * 16 + t) * 128 + e) * 128 + (scb >> 1), (char*)KW + o);
    }
    __syncthreads();

    f32x4 acc[2][8];
#pragma unroll
    for (int m = 0; m < 2; ++m)
#pragma unroll
        for (int n = 0; n < 8; ++n)
#pragma unroll
            for (int r = 0; r < 4; ++r) acc[m][n][r] = 0.f;

#pragma unroll
    for (int kk = 0; kk < 4; ++kk) {
        int kb = kk * 64 + ((lane >> 4) * 16);
        bf16x8 qf[2], wf[8];
#pragma unroll
        for (int m = 0; m < 2; ++m) {
            int r = w * 32 + m * 16 + (lane & 15);
            qf[m] = *(const bf16x8*)((const char*)Qs + (r << 8) + (kb ^ ((r & 7) << 4)));
        }
#pragma unroll
        for (int n = 0; n < 8; ++n) {
            int e = n * 16 + (lane & 15);
            wf[n] = *(const bf16x8*)((const char*)KW + (e << 8) + (kb ^ ((e & 7) << 4)));
        }
#pragma unroll
        for (int m = 0; m < 2; ++m)
#pragma unroll
            for (int n = 0; n < 8; ++n)
                acc[m][n] = MFMA16(qf[m], wf[n], acc[m][n]);
    }
#pragma unroll
    for (int m = 0; m < 2; ++m)
#pragma unroll
        for (int rg = 0; rg < 4; ++rg) {
            int i = qh * 128 + w * 32 + m * 16 + ((lane >> 4) * 4) + rg;
            float qd = __expf(-s * (float)(i + 1));
#pragma unroll
            for (int n = 0; n < 8; ++n) acc[m][n][rg] *= qd;
        }

    int jbmax = ((qh << 2) + w) >> 1;
    for (int jb = 0; jb < 4; ++jb) {
        __syncthreads();
#pragma unroll
        for (int it = 0; it < 4; ++it) {
            int o = (it * 256 + tid) * 16;
            int r = o >> 8, cb = o & 255, scb = cb ^ ((r & 7) << 4);
            gl16(qkv + (size_t)(t * 256 + jb * 64 + r) * 12288 + h * 384 + 128 + (scb >> 1),
                 (char*)Ks + o);
        }
#pragma unroll
        for (int it = 0; it < 4; ++it) {
            int o = (it * 256 + tid) * 16;
            int e = o >> 7, cb = o & 127, scb = cb ^ ((e & 7) << 4);
            gl16(vt + (size_t)(h * 128 + e) * 4096 + t * 256 + jb * 64 + (scb >> 1),
                 (char*)Vs + o);
        }
        __syncthreads();

        if (jb <= jbmax) {
            f32x4 sc[2][4];
#pragma unroll
            for (int m = 0; m < 2; ++m)
#pragma unroll
                for (int n = 0; n < 4; ++n)
#pragma unroll
                    for (int r = 0; r < 4; ++r) sc[m][n][r] = 0.f;
#pragma unroll
            for (int kk = 0; kk < 4; ++kk) {
                int kb = kk * 64 + ((lane >> 4) * 16);
                bf16x8 qf[2], kf[4];
#pragma unroll
                for (int m = 0; m < 2; ++m) {
                    int r = w * 32 + m * 16 + (lane & 15);
                    qf[m] = *(const bf16x8*)((const char*)Qs + (r << 8) + (kb ^ ((r & 7) << 4)));
                }
#pragma unroll
                for (int n = 0; n < 4; ++n) {
                    int r = n * 16 + (lane & 15);
                    kf[n] = *(const bf16x8*)((const char*)Ks + (r << 8) + (kb ^ ((r & 7) << 4)));
                }
#pragma unroll
                for (int m = 0; m < 2; ++m)
#pragma unroll
                    for (int n = 0; n < 4; ++n)
                        sc[m][n] = MFMA16(qf[m], kf[n], sc[m][n]);
            }
            unsigned short* Pw = Ps + w * 2048;
#pragma unroll
            for (int m = 0; m < 2; ++m)
#pragma unroll
                for (int n = 0; n < 4; ++n)
#pragma unroll
                    for (int rg = 0; rg < 4; ++rg) {
                        int il = m * 16 + ((lane >> 4) * 4) + rg;
                        int i = qh * 128 + w * 32 + il;
                        int jl = n * 16 + (lane & 15);
                        int j = jb * 64 + jl;
                        float v = 0.f;
                        if (i >= j) v = sc[m][n][rg] * __expf(-s * (float)(i - j));
                        int cb2 = (jl * 2) ^ ((il & 7) << 4);
                        *(unsigned short*)((char*)Pw + (il << 7) + cb2) = f2bf(v);
                    }
            asm volatile("s_waitcnt lgkmcnt(0)" ::: "memory");
#pragma unroll
            for (int kk = 0; kk < 2; ++kk) {
                int kb = kk * 64 + ((lane >> 4) * 16);
                bf16x8 pf[2], vf[8];
#pragma unroll
                for (int m = 0; m < 2; ++m) {
                    int il = m * 16 + (lane & 15);
                    pf[m] = *(const bf16x8*)((const char*)Pw + (il << 7) + (kb ^ ((il & 7) << 4)));
                }
#pragma unroll
                for (int n = 0; n < 8; ++n) {
                    int e = n * 16 + (lane & 15);
                    vf[n] = *(const bf16x8*)((const char*)Vs + (e << 7) + (kb ^ ((e & 7) << 4)));
                }
#pragma unroll
                for (int m = 0; m < 2; ++m)
#pragma unroll
                    for (int n = 0; n < 8; ++n)
                        acc[m][n] = MFMA16(pf[m], vf[n], acc[m][n]);
            }
        }
    }

#pragma unroll
    for (int m = 0; m < 2; ++m)
#pragma unroll
        for (int n = 0; n < 8; ++n)
#pragma unroll
            for (int rg = 0; rg < 4; ++rg) {
                int i = qh * 128 + w * 32 + m * 16 + ((lane >> 4) * 4) + rg;
                int col = h * 128 + n * 16 + (lane & 15);
                attn[(size_t)(t * 256 + i) * 4096 + col] = f2bf(acc[m][n][rg]);
            }
}

// ---------- RMSNorm + sigmoid-gate multiply ----------
__global__ __launch_bounds__(256) void rms_gate_kernel(const unsigned short* __restrict__ attn,
                                                       const unsigned short* __restrict__ gate,
                                                       const float* __restrict__ nw,
                                                       unsigned short* __restrict__ gated) {
    int row = blockIdx.x, tid = threadIdx.x;
    int lane = tid & 63, w = tid >> 6;
    const unsigned short* ar = attn + (size_t)row * 4096 + tid * 16;
    u16x8 a0 = *(const u16x8*)ar;
    u16x8 a1 = *(const u16x8*)(ar + 8);
    float v[16];
    float ss = 0.f;
#pragma unroll
    for (int j = 0; j < 8; ++j) { v[j] = bf2f(a0[j]); v[8 + j] = bf2f(a1[j]); }
#pragma unroll
    for (int j = 0; j < 16; ++j) ss += v[j] * v[j];
#pragma unroll
    for (int o = 32; o > 0; o >>= 1) ss += __shfl_xor(ss, o);
    __shared__ float red[4];
    if (lane == 0) red[w] = ss;
    __syncthreads();
    float tot = red[0] + red[1] + red[2] + red[3];
    float rs = rsqrtf(tot * (1.f / 4096.f) + 1e-5f);
    const unsigned short* gr = gate + (size_t)row * 4096 + tid * 16;
    u16x8 g0 = *(const u16x8*)gr;
    u16x8 g1 = *(const u16x8*)(gr + 8);
    const float* nwp = nw + tid * 16;
    u16x8 o0, o1;
#pragma unroll
    for (int j = 0; j < 8; ++j) {
        o0[j] = f2bf(v[j] * rs * nwp[j] * bf2f(g0[j]));
        o1[j] = f2bf(v[8 + j] * rs * nwp[8 + j] * bf2f(g1[j]));
    }
    unsigned short* gp = gated + (size_t)row * 4096 + tid * 16;
    *(u16x8*)gp = o0;
    *(u16x8*)(gp + 8) = o1;
}

// ---------- launcher ----------
extern "C" void kernel_launch(void* const* d_in, const int* in_sizes, int n_in,
                              void* d_out, int out_size, void* d_ws, size_t ws_size,
                              hipStream_t stream) {
    const float* hs       = (const float*)d_in[0];
    const float* w_qkv    = (const float*)d_in[1];
    const float* w_gate   = (const float*)d_in[2];
    const float* w_out    = (const float*)d_in[3];
    const float* nw       = (const float*)d_in[4];
    const float* slopes   = (const float*)d_in[5];
    const float* kv_cache = (const float*)d_in[6];
    float* out = (float*)d_out;
    char* ws = (char*)d_ws;

    unsigned short* hsb  = (unsigned short*)(ws + 0);           // 16 MB
    unsigned short* wqt  = (unsigned short*)(ws + 16777216);    // 48 MB [12288][2048]
    unsigned short* wgt  = (unsigned short*)(ws + 67108864);    // 16 MB (contiguous after wqt)
    unsigned short* wot  = (unsigned short*)(ws + 83886080);    // 16 MB [2048][4096]
    unsigned short* qkv  = (unsigned short*)(ws + 100663296);   // 96 MB [4096][12288]
    unsigned short* gate = (unsigned short*)(ws + 201326592);   // 32 MB [4096][4096]
    unsigned short* kts  = (unsigned short*)(ws + 234881024);   // 32 MB [32][128][4096]
    unsigned short* vt   = (unsigned short*)(ws + 268435456);   // 32 MB [32][128][4096]
    float*          U    = (float*)(ws + 301989888);            // 32 MB
    unsigned short* Wb   = (unsigned short*)(ws + 335544320);   // 16 MB
    unsigned short* attn  = wqt;  // reuse
    unsigned short* gated = qkv;  // reuse

    f32_to_bf16_kernel<<<4096, 256, 0, stream>>>(hs, hsb, 1048576);
    {
        dim3 g(192, 32);
        transpose_w_kernel<<<g, 256, 0, stream>>>(w_qkv, wqt, 2048, 12288);
    }
    {
        dim3 g(64, 32);
        transpose_w_kernel<<<g, 256, 0, stream>>>(w_gate, wgt, 2048, 4096);
    }
    {
        dim3 g(32, 64);
        transpose_w_kernel<<<g, 256, 0, stream>>>(w_out, wot, 4096, 2048);
    }
    // fused qkv+gate: M=4096, N=16384 combined, K=2048; 16x64 = 1024 blocks
    gemm_qkvgate_kernel<<<1024, 512, 0, stream>>>(hsb, wqt, qkv, gate, 2048, 64, 48);
    {
        dim3 g(64, 2, 32);
        kv_transpose_kernel<<<g, 256, 0, stream>>>(qkv, slopes, kts, vt);
    }
    kv_outer_kernel<<<512, 256, 0, stream>>>(kts, vt, U);
    kv_scan_kernel<<<512, 256, 0, stream>>>(kv_cache, U, slopes, Wb);
    attn_out_kernel<<<1024, 256, 0, stream>>>(qkv, vt, Wb, slopes, attn);
    rms_gate_kernel<<<4096, 256, 0, stream>>>(attn, gate, nw, gated);
    // out: M=4096 N=2048 K=4096, 128^2 tiles, 32x16 = 512 blocks, f32 out
    gemm_out_kernel<<<512, 256, 0, stream>>>(gated, wot, out, 2048, 4096, 16);
}

// Round 12
// 466.110 us; speedup vs baseline: 5.9256x; 5.9256x over previous
//
#include <hip/hip_runtime.h>
#include <stdint.h>

// ---------- types & helpers ----------
typedef __bf16 bf16x8 __attribute__((ext_vector_type(8)));
typedef float  f32x4  __attribute__((ext_vector_type(4)));
typedef unsigned short u16x8 __attribute__((ext_vector_type(8)));

__device__ __forceinline__ unsigned short f2bf(float f) {
    union { float f; uint32_t u; } x; x.f = f;
    uint32_t r = (x.u + 0x7FFFu + ((x.u >> 16) & 1u)) >> 16;
    return (unsigned short)r;
}
__device__ __forceinline__ float bf2f(unsigned short b) {
    union { uint32_t u; float f; } x; x.u = ((uint32_t)b) << 16;
    return x.f;
}

// global -> LDS direct (16B per lane). LDS dest: wave-uniform base + lane*16.
__device__ __forceinline__ void gl16(const void* g, void* l) {
    __builtin_amdgcn_global_load_lds(
        (const __attribute__((address_space(1))) void*)g,
        (__attribute__((address_space(3))) void*)(uint32_t)(uintptr_t)l,
        16, 0, 0);
}

#define MFMA16(a, b, c) __builtin_amdgcn_mfma_f32_16x16x32_bf16((a), (b), (c), 0, 0, 0)

// ---------- merged prep: hs f32->bf16 + 3 weight transposes ----------
// blocks [0,6144): w_qkv^T (192x32 tiles); [6144,8192): w_gate^T (64x32);
// [8192,10240): w_out^T (32x64); [10240,14336): hs f32->bf16 elementwise.
__global__ __launch_bounds__(256) void prep_kernel(const float* __restrict__ hs,
                                                   const float* __restrict__ w_qkv,
                                                   const float* __restrict__ w_gate,
                                                   const float* __restrict__ w_out,
                                                   unsigned short* __restrict__ hsb,
                                                   unsigned short* __restrict__ wqt,
                                                   unsigned short* __restrict__ wgt,
                                                   unsigned short* __restrict__ wot) {
    __shared__ float tile[64][65];
    int b = blockIdx.x, tid = threadIdx.x;
    if (b >= 10240) {
        int i = (b - 10240) * 256 + tid;
        float4 a = ((const float4*)hs)[2 * i];
        float4 c = ((const float4*)hs)[2 * i + 1];
        u16x8 o;
        o[0] = f2bf(a.x); o[1] = f2bf(a.y); o[2] = f2bf(a.z); o[3] = f2bf(a.w);
        o[4] = f2bf(c.x); o[5] = f2bf(c.y); o[6] = f2bf(c.z); o[7] = f2bf(c.w);
        ((u16x8*)hsb)[i] = o;
        return;
    }
    const float* in; unsigned short* out; int R, C, bx, by;
    if (b < 6144)      { in = w_qkv;  out = wqt; R = 2048; C = 12288; bx = b % 192; by = b / 192; }
    else if (b < 8192) { int bb = b - 6144; in = w_gate; out = wgt; R = 2048; C = 4096; bx = bb % 64; by = bb / 64; }
    else               { int bb = b - 8192; in = w_out;  out = wot; R = 4096; C = 2048; bx = bb % 32; by = bb / 32; }
    int c0 = bx * 64, r0 = by * 64;
    int tr = tid >> 4;
    int tc4 = (tid & 15) * 4;
#pragma unroll
    for (int it = 0; it < 4; ++it) {
        int r = it * 16 + tr;
        float4 v = *(const float4*)&in[(size_t)(r0 + r) * C + c0 + tc4];
        tile[r][tc4] = v.x; tile[r][tc4 + 1] = v.y;
        tile[r][tc4 + 2] = v.z; tile[r][tc4 + 3] = v.w;
    }
    __syncthreads();
#pragma unroll
    for (int it = 0; it < 4; ++it) {
        int c = it * 16 + tr;
        ushort4 o;
        o.x = f2bf(tile[tc4][c]);
        o.y = f2bf(tile[tc4 + 1][c]);
        o.z = f2bf(tile[tc4 + 2][c]);
        o.w = f2bf(tile[tc4 + 3][c]);
        *(ushort4*)&out[(size_t)(c0 + c) * R + r0 + tc4] = o;
    }
}

// ====== 256x256 register-pipelined 4-phase GEMM, fused qkv+gate (R10) =======
// BK=64, 128KB LDS, single barrier per K-tile (PH2: lgkm0+vmcnt0+bar).
__global__ __launch_bounds__(512, 2) void gemm_qkvgate_kernel(const unsigned short* __restrict__ A,
                                                              const unsigned short* __restrict__ Bt,
                                                              unsigned short* __restrict__ qkvp,
                                                              unsigned short* __restrict__ gatep,
                                                              int K, int NBN, int NQ) {
    __shared__ unsigned short Abuf[2][2][8192];  // [slot][half][128*64]
    __shared__ unsigned short Bbuf[2][2][8192];

    int bid = blockIdx.x;
    int xcd = bid & 7, kw = bid >> 3;            // 2D XCD-region swizzle
    int bm = (xcd & 3) * 4 + (kw & 3);
    int bn = (xcd >> 2) * (NBN >> 1) + (kw >> 2);
    int tid = threadIdx.x, lane = tid & 63, w = tid >> 6;
    int wr = w >> 2, wc = w & 3;

    int r0 = tid >> 3;
    int cbs = (tid & 7) << 4;
    int el0 = (cbs ^ ((r0 & 7) << 4)) >> 1;
    int r1 = 64 + r0;
    int el1 = (cbs ^ ((r1 & 7) << 4)) >> 1;
    int lo0 = tid * 16, lo1 = 8192 + tid * 16;

    const unsigned short* Ag0 = A + (size_t)(bm * 256) * K;
    const unsigned short* Ag1 = A + (size_t)(bm * 256 + 128) * K;
    const unsigned short* Bg0 = Bt + (size_t)(bn * 256) * K;
    const unsigned short* Bg1 = Bt + (size_t)(bn * 256 + 128) * K;

#define STAGE(src, dstHalf, k0)                                            \
    do {                                                                   \
        gl16((src) + (size_t)r0 * K + (k0) + el0, (char*)(dstHalf) + lo0); \
        gl16((src) + (size_t)r1 * K + (k0) + el1, (char*)(dstHalf) + lo1); \
    } while (0)

    int aRow = wr * 64 + (lane & 15);
    int bRow = wc * 32 + (lane & 15);
    int swz = (lane & 7) << 4;
    int cbb = (lane >> 4) << 4;

#define RD_A(slot, R, m, kk) \
    af[R][m][kk] = *(const bf16x8*)((const char*)Abuf[slot][R] + ((aRow + (m) * 16) << 7) + (((kk) * 64 + cbb) ^ swz))
#define RD_B(slot, Cq, n, kk) \
    bfr[Cq][n][kk] = *(const bf16x8*)((const char*)Bbuf[slot][Cq] + ((bRow + (n) * 16) << 7) + (((kk) * 64 + cbb) ^ swz))

#define QUAD(q, Rh, Cc)                                                       \
    do {                                                                      \
        _Pragma("unroll")                                                     \
        for (int m = 0; m < 4; ++m)                                           \
            _Pragma("unroll")                                                 \
            for (int n = 0; n < 2; ++n) {                                     \
                acc[q][m][n] = MFMA16(af[Rh][m][0], bfr[Cc][n][0], acc[q][m][n]); \
                acc[q][m][n] = MFMA16(af[Rh][m][1], bfr[Cc][n][1], acc[q][m][n]); \
            }                                                                 \
    } while (0)

    bf16x8 af[2][4][2];
    bf16x8 bfr[2][2][2];
    f32x4 acc[4][4][2];
#pragma unroll
    for (int q = 0; q < 4; ++q)
#pragma unroll
        for (int m = 0; m < 4; ++m)
#pragma unroll
            for (int n = 0; n < 2; ++n)
#pragma unroll
                for (int r = 0; r < 4; ++r) acc[q][m][n][r] = 0.f;

    int NT = K >> 6;
    STAGE(Ag0, Abuf[0][0], 0);
    STAGE(Bg0, Bbuf[0][0], 0);
    STAGE(Ag1, Abuf[0][1], 0);
    STAGE(Bg1, Bbuf[0][1], 0);
    STAGE(Ag0, Abuf[1][0], 64);
    STAGE(Bg0, Bbuf[1][0], 64);
    STAGE(Ag1, Abuf[1][1], 64);
    STAGE(Bg1, Bbuf[1][1], 64);
    asm volatile("s_waitcnt vmcnt(8)" ::: "memory");
    __builtin_amdgcn_s_barrier();
#pragma unroll
    for (int m = 0; m < 4; ++m) { RD_A(0, 0, m, 0); RD_A(0, 0, m, 1); }
#pragma unroll
    for (int n = 0; n < 2; ++n) { RD_B(0, 0, n, 0); RD_B(0, 0, n, 1); }

    for (int t = 0; t < NT; ++t) {
        int cur = t & 1, nx = cur ^ 1;
        bool rd = (t + 1 < NT);
        bool st = (t + 2 < NT);
        int ks = (t + 2) << 6;

        // ---- PH0: read afR1(t); Q0 gated on afR0+bC0 (issued 2 phases back)
#pragma unroll
        for (int m = 0; m < 4; ++m) { RD_A(cur, 1, m, 0); RD_A(cur, 1, m, 1); }
        asm volatile("s_waitcnt lgkmcnt(8)" ::: "memory");
        __builtin_amdgcn_sched_barrier(0);
        __builtin_amdgcn_s_setprio(1);
        QUAD(0, 0, 0);
        __builtin_amdgcn_s_setprio(0);

        // ---- PH1: read bC1(t); Q1 gated on afR1
#pragma unroll
        for (int n = 0; n < 2; ++n) { RD_B(cur, 1, n, 0); RD_B(cur, 1, n, 1); }
        asm volatile("s_waitcnt lgkmcnt(4)" ::: "memory");
        __builtin_amdgcn_sched_barrier(0);
        __builtin_amdgcn_s_setprio(1);
        QUAD(1, 1, 0);
        __builtin_amdgcn_s_setprio(0);

        // ---- PH2: tile-boundary drain; stage first half of tile t+2; read bC0(t+1)
        asm volatile("s_waitcnt lgkmcnt(0)" ::: "memory");
        asm volatile("s_waitcnt vmcnt(0)" ::: "memory");
        __builtin_amdgcn_s_barrier();
        if (st) {
            STAGE(Ag0, Abuf[cur][0], ks);
            STAGE(Bg0, Bbuf[cur][0], ks);
        }
        if (rd) {
#pragma unroll
            for (int n = 0; n < 2; ++n) { RD_B(nx, 0, n, 0); RD_B(nx, 0, n, 1); }
        }
        __builtin_amdgcn_s_setprio(1);
        QUAD(2, 0, 1);
        __builtin_amdgcn_s_setprio(0);

        // ---- PH3: stage second half of tile t+2; read afR0(t+1); Q3 all-reg
        if (st) {
            STAGE(Ag1, Abuf[cur][1], ks);
            STAGE(Bg1, Bbuf[cur][1], ks);
        }
        if (rd) {
#pragma unroll
            for (int m = 0; m < 4; ++m) { RD_A(nx, 0, m, 0); RD_A(nx, 0, m, 1); }
        }
        __builtin_amdgcn_s_setprio(1);
        QUAD(3, 1, 1);
        __builtin_amdgcn_s_setprio(0);
    }

    // epilogue: block-uniform output select
    bool isQ = (bn < NQ);
    unsigned short* outp = isQ ? qkvp : gatep;
    int Nout = isQ ? 12288 : 4096;
    int colb0 = (isQ ? bn : bn - NQ) * 256;
#pragma unroll
    for (int q = 0; q < 4; ++q) {
        const int R_ = q & 1, C_ = q >> 1;
#pragma unroll
        for (int m = 0; m < 4; ++m) {
            int row0 = bm * 256 + R_ * 128 + wr * 64 + m * 16 + ((lane >> 4) * 4);
#pragma unroll
            for (int n = 0; n < 2; ++n) {
                int col = colb0 + C_ * 128 + wc * 32 + n * 16 + (lane & 15);
#pragma unroll
                for (int rg = 0; rg < 4; ++rg) {
                    float v = acc[q][m][n][rg];
                    float sig = 1.f / (1.f + __expf(-v));
                    float r = isQ ? v * sig : sig;
                    outp[(size_t)(row0 + rg) * Nout + col] = f2bf(r);
                }
            }
        }
    }
#undef STAGE
#undef RD_A
#undef RD_B
#undef QUAD
}

// ====== 128x128 pipelined out-GEMM (R10) ====================================
__global__ __launch_bounds__(256, 2) void gemm_out_kernel(const unsigned short* __restrict__ A,
                                                          const unsigned short* __restrict__ Bt,
                                                          float* __restrict__ Cout,
                                                          int N, int K, int NBN) {
    __shared__ unsigned short Abuf[2][2][4096];
    __shared__ unsigned short Bbuf[2][2][4096];

    int bid = blockIdx.x, nwg = gridDim.x;
    int wg = (bid & 7) * (nwg >> 3) + (bid >> 3);
    int bm = wg / NBN, bn = wg % NBN;
    int tid = threadIdx.x, lane = tid & 63, w = tid >> 6;
    int wr = w >> 1, wc = w & 1;

    int r0 = tid >> 3;
    int cbs = (tid & 7) << 4;
    int el0 = (cbs ^ ((r0 & 7) << 4)) >> 1;
    int r1 = 32 + r0;
    int el1 = (cbs ^ ((r1 & 7) << 4)) >> 1;
    int lo0 = tid * 16, lo1 = 4096 + tid * 16;

    const unsigned short* Ag0 = A + (size_t)(bm * 128) * K;
    const unsigned short* Ag1 = A + (size_t)(bm * 128 + 64) * K;
    const unsigned short* Bg0 = Bt + (size_t)(bn * 128) * K;
    const unsigned short* Bg1 = Bt + (size_t)(bn * 128 + 64) * K;

#define STAGE(src, dstHalf, k0)                                            \
    do {                                                                   \
        gl16((src) + (size_t)r0 * K + (k0) + el0, (char*)(dstHalf) + lo0); \
        gl16((src) + (size_t)r1 * K + (k0) + el1, (char*)(dstHalf) + lo1); \
    } while (0)

    int aRow = wr * 32 + (lane & 15);
    int bRow = wc * 32 + (lane & 15);
    int swz = (lane & 7) << 4;
    int cbb = (lane >> 4) << 4;

#define RD_A(slot, R, m, kk) \
    af[R][m][kk] = *(const bf16x8*)((const char*)Abuf[slot][R] + ((aRow + (m) * 16) << 7) + (((kk) * 64 + cbb) ^ swz))
#define RD_B(slot, Cq, n, kk) \
    bfr[Cq][n][kk] = *(const bf16x8*)((const char*)Bbuf[slot][Cq] + ((bRow + (n) * 16) << 7) + (((kk) * 64 + cbb) ^ swz))

#define QUAD(q, Rh, Cc)                                                       \
    do {                                                                      \
        _Pragma("unroll")                                                     \
        for (int m = 0; m < 2; ++m)                                           \
            _Pragma("unroll")                                                 \
            for (int n = 0; n < 2; ++n) {                                     \
                acc[q][m][n] = MFMA16(af[Rh][m][0], bfr[Cc][n][0], acc[q][m][n]); \
                acc[q][m][n] = MFMA16(af[Rh][m][1], bfr[Cc][n][1], acc[q][m][n]); \
            }                                                                 \
    } while (0)

    bf16x8 af[2][2][2];
    bf16x8 bfr[2][2][2];
    f32x4 acc[4][2][2];
#pragma unroll
    for (int q = 0; q < 4; ++q)
#pragma unroll
        for (int m = 0; m < 2; ++m)
#pragma unroll
            for (int n = 0; n < 2; ++n)
#pragma unroll
                for (int r = 0; r < 4; ++r) acc[q][m][n][r] = 0.f;

    int NT = K >> 6;
    STAGE(Ag0, Abuf[0][0], 0);
    STAGE(Bg0, Bbuf[0][0], 0);
    STAGE(Ag1, Abuf[0][1], 0);
    STAGE(Bg1, Bbuf[0][1], 0);
    STAGE(Ag0, Abuf[1][0], 64);
    STAGE(Bg0, Bbuf[1][0], 64);
    STAGE(Ag1, Abuf[1][1], 64);
    STAGE(Bg1, Bbuf[1][1], 64);
    asm volatile("s_waitcnt vmcnt(8)" ::: "memory");
    __builtin_amdgcn_s_barrier();
#pragma unroll
    for (int m = 0; m < 2; ++m) { RD_A(0, 0, m, 0); RD_A(0, 0, m, 1); }
#pragma unroll
    for (int n = 0; n < 2; ++n) { RD_B(0, 0, n, 0); RD_B(0, 0, n, 1); }

    for (int t = 0; t < NT; ++t) {
        int cur = t & 1, nx = cur ^ 1;
        bool rd = (t + 1 < NT);
        bool st = (t + 2 < NT);
        int ks = (t + 2) << 6;

        // ---- PH0
#pragma unroll
        for (int m = 0; m < 2; ++m) { RD_A(cur, 1, m, 0); RD_A(cur, 1, m, 1); }
        asm volatile("s_waitcnt lgkmcnt(4)" ::: "memory");
        __builtin_amdgcn_sched_barrier(0);
        __builtin_amdgcn_s_setprio(1);
        QUAD(0, 0, 0);
        __builtin_amdgcn_s_setprio(0);

        // ---- PH1
#pragma unroll
        for (int n = 0; n < 2; ++n) { RD_B(cur, 1, n, 0); RD_B(cur, 1, n, 1); }
        asm volatile("s_waitcnt lgkmcnt(4)" ::: "memory");
        __builtin_amdgcn_sched_barrier(0);
        __builtin_amdgcn_s_setprio(1);
        QUAD(1, 1, 0);
        __builtin_amdgcn_s_setprio(0);

        // ---- PH2: single tile-boundary drain
        asm volatile("s_waitcnt lgkmcnt(0)" ::: "memory");
        asm volatile("s_waitcnt vmcnt(0)" ::: "memory");
        __builtin_amdgcn_s_barrier();
        if (st) {
            STAGE(Ag0, Abuf[cur][0], ks);
            STAGE(Bg0, Bbuf[cur][0], ks);
        }
        if (rd) {
#pragma unroll
            for (int n = 0; n < 2; ++n) { RD_B(nx, 0, n, 0); RD_B(nx, 0, n, 1); }
        }
        __builtin_amdgcn_s_setprio(1);
        QUAD(2, 0, 1);
        __builtin_amdgcn_s_setprio(0);

        // ---- PH3
        if (st) {
            STAGE(Ag1, Abuf[cur][1], ks);
            STAGE(Bg1, Bbuf[cur][1], ks);
        }
        if (rd) {
#pragma unroll
            for (int m = 0; m < 2; ++m) { RD_A(nx, 0, m, 0); RD_A(nx, 0, m, 1); }
        }
        __builtin_amdgcn_s_setprio(1);
        QUAD(3, 1, 1);
        __builtin_amdgcn_s_setprio(0);
    }

    // epilogue (f32 out)
#pragma unroll
    for (int q = 0; q < 4; ++q) {
        const int R_ = q & 1, C_ = q >> 1;
#pragma unroll
        for (int m = 0; m < 2; ++m) {
            int row0 = bm * 128 + R_ * 64 + wr * 32 + m * 16 + ((lane >> 4) * 4);
#pragma unroll
            for (int n = 0; n < 2; ++n) {
                int col = bn * 128 + C_ * 64 + wc * 32 + n * 16 + (lane & 15);
#pragma unroll
                for (int rg = 0; rg < 4; ++rg)
                    Cout[(size_t)(row0 + rg) * N + col] = acc[q][m][n][rg];
            }
        }
    }
#undef STAGE
#undef RD_A
#undef RD_B
#undef QUAD
}

// ---------- qkv -> kts (scaled, transposed), vt (transposed); 64x64 tiles ----------
__global__ __launch_bounds__(256) void kv_transpose_kernel(const unsigned short* __restrict__ qkv,
                                                           const float* __restrict__ slopes,
                                                           unsigned short* __restrict__ kts,
                                                           unsigned short* __restrict__ vt) {
    __shared__ unsigned short tk[64][66];
    __shared__ unsigned short tv[64][66];
    int n0 = blockIdx.x * 64, d0 = blockIdx.y * 64, h = blockIdx.z;
    float s = slopes[h];
    int tid = threadIdx.x;
    int tr = tid >> 4;
    int tc4 = (tid & 15) * 4;
#pragma unroll
    for (int it = 0; it < 4; ++it) {
        int r = it * 16 + tr;
        int n = n0 + r;
        size_t rowb = (size_t)n * 12288 + h * 384;
        float sc = __expf(-s * (float)(255 - (n & 255)));
        ushort4 k4 = *(const ushort4*)&qkv[rowb + 128 + d0 + tc4];
        ushort4 v4 = *(const ushort4*)&qkv[rowb + 256 + d0 + tc4];
        tk[r][tc4 + 0] = f2bf(bf2f(k4.x) * sc);
        tk[r][tc4 + 1] = f2bf(bf2f(k4.y) * sc);
        tk[r][tc4 + 2] = f2bf(bf2f(k4.z) * sc);
        tk[r][tc4 + 3] = f2bf(bf2f(k4.w) * sc);
        tv[r][tc4 + 0] = v4.x;
        tv[r][tc4 + 1] = v4.y;
        tv[r][tc4 + 2] = v4.z;
        tv[r][tc4 + 3] = v4.w;
    }
    __syncthreads();
#pragma unroll
    for (int it = 0; it < 4; ++it) {
        int c = it * 16 + tr;
        ushort4 ok, ov;
        ok.x = tk[tc4 + 0][c]; ok.y = tk[tc4 + 1][c];
        ok.z = tk[tc4 + 2][c]; ok.w = tk[tc4 + 3][c];
        ov.x = tv[tc4 + 0][c]; ov.y = tv[tc4 + 1][c];
        ov.z = tv[tc4 + 2][c]; ov.w = tv[tc4 + 3][c];
        size_t ob = (size_t)(h * 128 + d0 + c) * 4096 + n0 + tc4;
        *(ushort4*)&kts[ob] = ok;
        *(ushort4*)&vt[ob] = ov;
    }
}

// ---------- per-block KV outer product ----------
__global__ __launch_bounds__(256) void kv_outer_kernel(const unsigned short* __restrict__ kts,
                                                       const unsigned short* __restrict__ vt,
                                                       float* __restrict__ U) {
    __shared__ unsigned short Kc[128 * 64];
    __shared__ unsigned short Vc[128 * 64];
    int blk = blockIdx.x;
    int h = blk & 31, t = blk >> 5;
    int tid = threadIdx.x, lane = tid & 63, w = tid >> 6;

    f32x4 acc[2][8];
#pragma unroll
    for (int m = 0; m < 2; ++m)
#pragma unroll
        for (int n = 0; n < 8; ++n)
#pragma unroll
            for (int r = 0; r < 4; ++r) acc[m][n][r] = 0.f;

    for (int ks = 0; ks < 4; ++ks) {
        __syncthreads();
#pragma unroll
        for (int it = 0; it < 4; ++it) {
            int slot = it * 256 + tid;
            int o = slot * 16;
            int r = o >> 7;
            int cb = o & 127;
            int scb = cb ^ ((r & 7) << 4);
            size_t j = (size_t)t * 256 + ks * 64 + (scb >> 1);
            gl16(kts + (size_t)(h * 128 + r) * 4096 + j, (char*)Kc + o);
            gl16(vt + (size_t)(h * 128 + r) * 4096 + j, (char*)Vc + o);
        }
        __syncthreads();
#pragma unroll
        for (int kk = 0; kk < 2; ++kk) {
            int kb = kk * 64 + ((lane >> 4) * 16);
            bf16x8 vf[2], kf[8];
#pragma unroll
            for (int m = 0; m < 2; ++m) {
                int e = w * 32 + m * 16 + (lane & 15);
                vf[m] = *(const bf16x8*)((const char*)Vc + (e << 7) + (kb ^ ((e & 7) << 4)));
            }
#pragma unroll
            for (int n = 0; n < 8; ++n) {
                int d = n * 16 + (lane & 15);
                kf[n] = *(const bf16x8*)((const char*)Kc + (d << 7) + (kb ^ ((d & 7) << 4)));
            }
#pragma unroll
            for (int m = 0; m < 2; ++m)
#pragma unroll
                for (int n = 0; n < 8; ++n)
                    acc[m][n] = MFMA16(vf[m], kf[n], acc[m][n]);
        }
    }
    size_t base = (size_t)(h * 16 + t) * 16384;
#pragma unroll
    for (int m = 0; m < 2; ++m)
#pragma unroll
        for (int n = 0; n < 8; ++n)
#pragma unroll
            for (int r = 0; r < 4; ++r) {
                int e = w * 32 + m * 16 + ((lane >> 4) * 4) + r;
                int d = n * 16 + (lane & 15);
                U[base + (size_t)e * 128 + d] = acc[m][n][r];
            }
}

// ---------- parallel scan: 32 heads x 16 chunks of 1024 ----------
__global__ __launch_bounds__(256) void kv_scan_kernel(const float* __restrict__ kv_cache,
                                                      const float* __restrict__ U,
                                                      const float* __restrict__ slopes,
                                                      unsigned short* __restrict__ Wb) {
    __shared__ float Tt[8][132];
    int h = blockIdx.x >> 4;
    int c = blockIdx.x & 15;
    int c0 = c * 1024, e0 = c * 8;
    int tid = threadIdx.x;
    float s = slopes[h];
    float bd = __expf(-s * 256.f);
    size_t hb = (size_t)h * 16384;
#pragma unroll
    for (int it = 0; it < 4; ++it) {
        int d = it * 32 + (tid >> 3);
        Tt[tid & 7][d] = kv_cache[hb + (size_t)d * 128 + e0 + (tid & 7)];
    }
    __syncthreads();
    float wst[4];
#pragma unroll
    for (int i = 0; i < 4; ++i) {
        int local = i * 256 + tid;
        wst[i] = Tt[local >> 7][local & 127];
    }
    for (int t = 0; t < 16; ++t) {
        size_t base = (size_t)(h * 16 + t) * 16384 + c0;
#pragma unroll
        for (int i = 0; i < 4; ++i) {
            int idx = i * 256 + tid;
            Wb[base + idx] = f2bf(wst[i]);
            wst[i] = bd * wst[i] + U[base + idx];
        }
    }
}

// ---------- fused attention block kernel: QBLK=128, 80KB LDS, 2 WG/CU ----------
__global__ __launch_bounds__(256, 2) void attn_out_kernel(const unsigned short* __restrict__ qkv,
                                                          const unsigned short* __restrict__ vt,
                                                          const unsigned short* __restrict__ Wb,
                                                          const float* __restrict__ slopes,
                                                          unsigned short* __restrict__ attn) {
    __shared__ unsigned short lds[40960];  // 80 KB
    unsigned short* Qs = lds;
    unsigned short* Ps = lds + 16384;
    unsigned short* KW = lds + 24576;
    unsigned short* Ks = KW;
    unsigned short* Vs = KW + 8192;

    int blk = blockIdx.x;
    int h = blk & 31, tq = blk >> 5;
    int t = tq >> 1, qh = tq & 1;
    float s = slopes[h];
    int tid = threadIdx.x, lane = tid & 63, w = tid >> 6;
    int rowbase = t * 256 + qh * 128;

#pragma unroll
    for (int it = 0; it < 8; ++it) {
        int o = (it * 256 + tid) * 16;
        int r = o >> 8, cb = o & 255, scb = cb ^ ((r & 7) << 4);
        gl16(qkv + (size_t)(rowbase + r) * 12288 + h * 384 + (scb >> 1), (char*)Qs + o);
    }
#pragma unroll
    for (int it = 0; it < 8; ++it) {
        int o = (it * 256 + tid) * 16;
        int e = o >> 8, cb = o & 255, scb = cb ^ ((e & 7) << 4);
        gl16(Wb + (size_t)((h * 16 + t) * 128 + e) * 128 + (scb >> 1), (char*)KW + o);
    }
    __syncthreads();

    f32x4 acc[2][8];
#pragma unroll
    for (int m = 0; m < 2; ++m)
#pragma unroll
        for (int n = 0; n < 8; ++n)
#pragma unroll
            for (int r = 0; r < 4; ++r) acc[m][n][r] = 0.f;

#pragma unroll
    for (int kk = 0; kk < 4; ++kk) {
        int kb = kk * 64 + ((lane >> 4) * 16);
        bf16x8 qf[2], wf[8];
#pragma unroll
        for (int m = 0; m < 2; ++m) {
            int r = w * 32 + m * 16 + (lane & 15);
            qf[m] = *(const bf16x8*)((const char*)Qs + (r << 8) + (kb ^ ((r & 7) << 4)));
        }
#pragma unroll
        for (int n = 0; n < 8; ++n) {
            int e = n * 16 + (lane & 15);
            wf[n] = *(const bf16x8*)((const char*)KW + (e << 8) + (kb ^ ((e & 7) << 4)));
        }
#pragma unroll
        for (int m = 0; m < 2; ++m)
#pragma unroll
            for (int n = 0; n < 8; ++n)
                acc[m][n] = MFMA16(qf[m], wf[n], acc[m][n]);
    }
#pragma unroll
    for (int m = 0; m < 2; ++m)
#pragma unroll
        for (int rg = 0; rg < 4; ++rg) {
            int i = qh * 128 + w * 32 + m * 16 + ((lane >> 4) * 4) + rg;
            float qd = __expf(-s * (float)(i + 1));
#pragma unroll
            for (int n = 0; n < 8; ++n) acc[m][n][rg] *= qd;
        }

    int jbmax = ((qh << 2) + w) >> 1;
    for (int jb = 0; jb < 4; ++jb) {
        __syncthreads();
#pragma unroll
        for (int it = 0; it < 4; ++it) {
            int o = (it * 256 + tid) * 16;
            int r = o >> 8, cb = o & 255, scb = cb ^ ((r & 7) << 4);
            gl16(qkv + (size_t)(t * 256 + jb * 64 + r) * 12288 + h * 384 + 128 + (scb >> 1),
                 (char*)Ks + o);
        }
#pragma unroll
        for (int it = 0; it < 4; ++it) {
            int o = (it * 256 + tid) * 16;
            int e = o >> 7, cb = o & 127, scb = cb ^ ((e & 7) << 4);
            gl16(vt + (size_t)(h * 128 + e) * 4096 + t * 256 + jb * 64 + (scb >> 1),
                 (char*)Vs + o);
        }
        __syncthreads();

        if (jb <= jbmax) {
            f32x4 sc[2][4];
#pragma unroll
            for (int m = 0; m < 2; ++m)
#pragma unroll
                for (int n = 0; n < 4; ++n)
#pragma unroll
                    for (int r = 0; r < 4; ++r) sc[m][n][r] = 0.f;
#pragma unroll
            for (int kk = 0; kk < 4; ++kk) {
                int kb = kk * 64 + ((lane >> 4) * 16);
                bf16x8 qf[2], kf[4];
#pragma unroll
                for (int m = 0; m < 2; ++m) {
                    int r = w * 32 + m * 16 + (lane & 15);
                    qf[m] = *(const bf16x8*)((const char*)Qs + (r << 8) + (kb ^ ((r & 7) << 4)));
                }
#pragma unroll
                for (int n = 0; n < 4; ++n) {
                    int r = n * 16 + (lane & 15);
                    kf[n] = *(const bf16x8*)((const char*)Ks + (r << 8) + (kb ^ ((r & 7) << 4)));
                }
#pragma unroll
                for (int m = 0; m < 2; ++m)
#pragma unroll
                    for (int n = 0; n < 4; ++n)
                        sc[m][n] = MFMA16(qf[m], kf[n], sc[m][n]);
            }
            unsigned short* Pw = Ps + w * 2048;
#pragma unroll
            for (int m = 0; m < 2; ++m)
#pragma unroll
                for (int n = 0; n < 4; ++n)
#pragma unroll
                    for (int rg = 0; rg < 4; ++rg) {
                        int il = m * 16 + ((lane >> 4) * 4) + rg;
                        int i = qh * 128 + w * 32 + il;
                        int jl = n * 16 + (lane & 15);
                        int j = jb * 64 + jl;
                        float v = 0.f;
                        if (i >= j) v = sc[m][n][rg] * __expf(-s * (float)(i - j));
                        int cb2 = (jl * 2) ^ ((il & 7) << 4);
                        *(unsigned short*)((char*)Pw + (il << 7) + cb2) = f2bf(v);
                    }
            asm volatile("s_waitcnt lgkmcnt(0)" ::: "memory");
#pragma unroll
            for (int kk = 0; kk < 2; ++kk) {
                int kb = kk * 64 + ((lane >> 4) * 16);
                bf16x8 pf[2], vf[8];
#pragma unroll
                for (int m = 0; m < 2; ++m) {
                    int il = m * 16 + (lane & 15);
                    pf[m] = *(const bf16x8*)((const char*)Pw + (il << 7) + (kb ^ ((il & 7) << 4)));
                }
#pragma unroll
                for (int n = 0; n < 8; ++n) {
                    int e = n * 16 + (lane & 15);
                    vf[n] = *(const bf16x8*)((const char*)Vs + (e << 7) + (kb ^ ((e & 7) << 4)));
                }
#pragma unroll
                for (int m = 0; m < 2; ++m)
#pragma unroll
                    for (int n = 0; n < 8; ++n)
                        acc[m][n] = MFMA16(pf[m], vf[n], acc[m][n]);
            }
        }
    }

#pragma unroll
    for (int m = 0; m < 2; ++m)
#pragma unroll
        for (int n = 0; n < 8; ++n)
#pragma unroll
            for (int rg = 0; rg < 4; ++rg) {
                int i = qh * 128 + w * 32 + m * 16 + ((lane >> 4) * 4) + rg;
                int col = h * 128 + n * 16 + (lane & 15);
                attn[(size_t)(t * 256 + i) * 4096 + col] = f2bf(acc[m][n][rg]);
            }
}

// ---------- RMSNorm + sigmoid-gate multiply ----------
__global__ __launch_bounds__(256) void rms_gate_kernel(const unsigned short* __restrict__ attn,
                                                       const unsigned short* __restrict__ gate,
                                                       const float* __restrict__ nw,
                                                       unsigned short* __restrict__ gated) {
    int row = blockIdx.x, tid = threadIdx.x;
    int lane = tid & 63, w = tid >> 6;
    const unsigned short* ar = attn + (size_t)row * 4096 + tid * 16;
    u16x8 a0 = *(const u16x8*)ar;
    u16x8 a1 = *(const u16x8*)(ar + 8);
    float v[16];
    float ss = 0.f;
#pragma unroll
    for (int j = 0; j < 8; ++j) { v[j] = bf2f(a0[j]); v[8 + j] = bf2f(a1[j]); }
#pragma unroll
    for (int j = 0; j < 16; ++j) ss += v[j] * v[j];
#pragma unroll
    for (int o = 32; o > 0; o >>= 1) ss += __shfl_xor(ss, o);
    __shared__ float red[4];
    if (lane == 0) red[w] = ss;
    __syncthreads();
    float tot = red[0] + red[1] + red[2] + red[3];
    float rs = rsqrtf(tot * (1.f / 4096.f) + 1e-5f);
    const unsigned short* gr = gate + (size_t)row * 4096 + tid * 16;
    u16x8 g0 = *(const u16x8*)gr;
    u16x8 g1 = *(const u16x8*)(gr + 8);
    const float* nwp = nw + tid * 16;
    u16x8 o0, o1;
#pragma unroll
    for (int j = 0; j < 8; ++j) {
        o0[j] = f2bf(v[j] * rs * nwp[j] * bf2f(g0[j]));
        o1[j] = f2bf(v[8 + j] * rs * nwp[8 + j] * bf2f(g1[j]));
    }
    unsigned short* gp = gated + (size_t)row * 4096 + tid * 16;
    *(u16x8*)gp = o0;
    *(u16x8*)(gp + 8) = o1;
}

// ---------- launcher ----------
extern "C" void kernel_launch(void* const* d_in, const int* in_sizes, int n_in,
                              void* d_out, int out_size, void* d_ws, size_t ws_size,
                              hipStream_t stream) {
    const float* hs       = (const float*)d_in[0];
    const float* w_qkv    = (const float*)d_in[1];
    const float* w_gate   = (const float*)d_in[2];
    const float* w_out    = (const float*)d_in[3];
    const float* nw       = (const float*)d_in[4];
    const float* slopes   = (const float*)d_in[5];
    const float* kv_cache = (const float*)d_in[6];
    float* out = (float*)d_out;
    char* ws = (char*)d_ws;

    unsigned short* hsb  = (unsigned short*)(ws + 0);           // 16 MB
    unsigned short* wqt  = (unsigned short*)(ws + 16777216);    // 48 MB [12288][2048]
    unsigned short* wgt  = (unsigned short*)(ws + 67108864);    // 16 MB (contiguous after wqt)
    unsigned short* wot  = (unsigned short*)(ws + 83886080);    // 16 MB [2048][4096]
    unsigned short* qkv  = (unsigned short*)(ws + 100663296);   // 96 MB [4096][12288]
    unsigned short* gate = (unsigned short*)(ws + 201326592);   // 32 MB [4096][4096]
    unsigned short* kts  = (unsigned short*)(ws + 234881024);   // 32 MB [32][128][4096]
    unsigned short* vt   = (unsigned short*)(ws + 268435456);   // 32 MB [32][128][4096]
    float*          U    = (float*)(ws + 301989888);            // 32 MB
    unsigned short* Wb   = (unsigned short*)(ws + 335544320);   // 16 MB
    unsigned short* attn  = wqt;  // reuse
    unsigned short* gated = qkv;  // reuse

    prep_kernel<<<14336, 256, 0, stream>>>(hs, w_qkv, w_gate, w_out, hsb, wqt, wgt, wot);
    // fused qkv+gate: M=4096, N=16384 combined, K=2048; 16x64 = 1024 blocks
    gemm_qkvgate_kernel<<<1024, 512, 0, stream>>>(hsb, wqt, qkv, gate, 2048, 64, 48);
    {
        dim3 g(64, 2, 32);
        kv_transpose_kernel<<<g, 256, 0, stream>>>(qkv, slopes, kts, vt);
    }
    kv_outer_kernel<<<512, 256, 0, stream>>>(kts, vt, U);
    kv_scan_kernel<<<512, 256, 0, stream>>>(kv_cache, U, slopes, Wb);
    attn_out_kernel<<<1024, 256, 0, stream>>>(qkv, vt, Wb, slopes, attn);
    rms_gate_kernel<<<4096, 256, 0, stream>>>(attn, gate, nw, gated);
    // out: M=4096 N=2048 K=4096, 128^2 tiles, 32x16 = 512 blocks, f32 out
    gemm_out_kernel<<<512, 256, 0, stream>>>(gated, wot, out, 2048, 4096, 16);
}